// Round 1
// baseline (1998.490 us; speedup 1.0000x reference)
//
#include <hip/hip_runtime.h>
#include <hip/hip_bf16.h>
#include <math.h>

// ---- problem constants ----
#define BATCH   2
#define SEQLEN  1024
#define DMODEL  1024
#define DINNER  2048
#define DSTATE  64
#define DTRANK  64
#define NLAYERS 2
#define BL      (BATCH * SEQLEN)          // 2048 rows
#define XZ_N    (2 * DINNER)              // 4096
#define XDBL_N  (DTRANK + 2 * DSTATE)     // 192

// ---------------------------------------------------------------------------
// Tiled f32 GEMM:  C[M,N] = A[M,K] * W[N,K]^T    (A row-major lda, W row-major K)
// 64x64 tile, 256 threads, 4x4 accum/thread, BK=16.
// EPI: 0 = none, 1 = bias + softplus
// ---------------------------------------------------------------------------
template<int EPI>
__global__ __launch_bounds__(256) void gemm_nt(
    const float* __restrict__ A, int lda,
    const float* __restrict__ W,          // [N,K] row-major
    const float* __restrict__ bias,       // [N] or nullptr
    float* __restrict__ C, int ldc, int K)
{
    __shared__ float As[16][68];
    __shared__ float Ws[16][68];
    const int tid = threadIdx.x;
    const int tx = tid & 15, ty = tid >> 4;
    const int m0 = blockIdx.y * 64, n0 = blockIdx.x * 64;
    const int lr = tid >> 2;            // 0..63 row within tile
    const int lk = (tid & 3) << 2;      // 0,4,8,12 k-offset

    const float* Ap = A + (size_t)(m0 + lr) * lda + lk;
    const float* Wp = W + (size_t)(n0 + lr) * K + lk;

    float acc[4][4] = {};

    for (int k0 = 0; k0 < K; k0 += 16) {
        float4 av = *(const float4*)(Ap + k0);
        float4 wv = *(const float4*)(Wp + k0);
        As[lk + 0][lr] = av.x; As[lk + 1][lr] = av.y;
        As[lk + 2][lr] = av.z; As[lk + 3][lr] = av.w;
        Ws[lk + 0][lr] = wv.x; Ws[lk + 1][lr] = wv.y;
        Ws[lk + 2][lr] = wv.z; Ws[lk + 3][lr] = wv.w;
        __syncthreads();
#pragma unroll
        for (int kk = 0; kk < 16; ++kk) {
            float4 a = *(const float4*)&As[kk][ty << 2];
            float4 b = *(const float4*)&Ws[kk][tx << 2];
            acc[0][0] += a.x * b.x; acc[0][1] += a.x * b.y;
            acc[0][2] += a.x * b.z; acc[0][3] += a.x * b.w;
            acc[1][0] += a.y * b.x; acc[1][1] += a.y * b.y;
            acc[1][2] += a.y * b.z; acc[1][3] += a.y * b.w;
            acc[2][0] += a.z * b.x; acc[2][1] += a.z * b.y;
            acc[2][2] += a.z * b.z; acc[2][3] += a.z * b.w;
            acc[3][0] += a.w * b.x; acc[3][1] += a.w * b.y;
            acc[3][2] += a.w * b.z; acc[3][3] += a.w * b.w;
        }
        __syncthreads();
    }

    const int n = n0 + (tx << 2);
#pragma unroll
    for (int i = 0; i < 4; ++i) {
        float4 v = make_float4(acc[i][0], acc[i][1], acc[i][2], acc[i][3]);
        if (EPI == 1) {
            v.x += bias[n + 0]; v.y += bias[n + 1];
            v.z += bias[n + 2]; v.w += bias[n + 3];
            v.x = v.x > 20.f ? v.x : log1pf(expf(v.x));
            v.y = v.y > 20.f ? v.y : log1pf(expf(v.y));
            v.z = v.z > 20.f ? v.z : log1pf(expf(v.z));
            v.w = v.w > 20.f ? v.w : log1pf(expf(v.w));
        }
        *(float4*)&C[(size_t)(m0 + (ty << 2) + i) * ldc + n] = v;
    }
}

// ---------------------------------------------------------------------------
// Causal depthwise conv (K=4) + bias + SiLU.  Reads u-half of xz [BL, 4096],
// writes u [BL, 2048].
// ---------------------------------------------------------------------------
__global__ __launch_bounds__(256) void conv_silu_kernel(
    const float* __restrict__ xz, const float* __restrict__ cw,
    const float* __restrict__ cb, float* __restrict__ u)
{
    int idx = blockIdx.x * 256 + threadIdx.x;
    if (idx >= BL * DINNER) return;
    int d = idx & (DINNER - 1);
    int m = idx >> 11;              // b*L + t
    int t = m & (SEQLEN - 1);
    float acc = cb[d];
#pragma unroll
    for (int k = 0; k < 4; ++k) {
        int tt = t - 3 + k;
        if (tt >= 0)
            acc += xz[(size_t)(m - 3 + k) * XZ_N + d] * cw[d * 4 + k];
    }
    u[idx] = acc / (1.f + expf(-acc));   // silu
}

// ---------------------------------------------------------------------------
// Selective scan. One wave per (b,d) channel, lane = state index s (dS=64).
// 4 waves / block.  Software-pipelined next-step loads.
// ---------------------------------------------------------------------------
__global__ __launch_bounds__(256) void scan_kernel(
    const float* __restrict__ u,      // [BL, DINNER]
    const float* __restrict__ dt,     // [BL, DINNER]
    const float* __restrict__ xdbl,   // [BL, 192] : [dt_in | B | C]
    const float* __restrict__ A_log,  // [DINNER, DSTATE] (layer slice)
    const float* __restrict__ D_skip, // [DINNER]
    float* __restrict__ y)            // [BL, DINNER]
{
    const int wave = threadIdx.x >> 6;
    const int lane = threadIdx.x & 63;
    const int c = blockIdx.x * 4 + wave;     // 0..4095
    const int b = c >> 11;
    const int d = c & (DINNER - 1);

    const float Av = -expf(A_log[d * DSTATE + lane]);
    const float Dk = D_skip[d];

    const float* dt_p = dt + (size_t)b * SEQLEN * DINNER + d;
    const float* u_p  = u  + (size_t)b * SEQLEN * DINNER + d;
    const float* bc_p = xdbl + (size_t)b * SEQLEN * XDBL_N + DTRANK + lane;
    float* y_p = y + (size_t)b * SEQLEN * DINNER + d;

    float h = 0.f;
    float dtv = dt_p[0];
    float uv  = u_p[0];
    float Bt  = bc_p[0];
    float Ct  = bc_p[DSTATE];

    for (int t = 0; t < SEQLEN; ++t) {
        float dtn = 0.f, un = 0.f, Bn = 0.f, Cn = 0.f;
        if (t < SEQLEN - 1) {
            dtn = dt_p[(t + 1) * DINNER];
            un  = u_p[(t + 1) * DINNER];
            Bn  = bc_p[(t + 1) * XDBL_N];
            Cn  = bc_p[(t + 1) * XDBL_N + DSTATE];
        }
        float dA = __expf(dtv * Av);
        h = h * dA + (dtv * uv) * Bt;
        float p = h * Ct;
#pragma unroll
        for (int off = 32; off; off >>= 1) p += __shfl_xor(p, off, 64);
        if (lane == 0) y_p[t * DINNER] = p + uv * Dk;
        dtv = dtn; uv = un; Bt = Bn; Ct = Cn;
    }
}

// ---------------------------------------------------------------------------
// Gate: y *= silu(z), z = second half of xz.
// ---------------------------------------------------------------------------
__global__ __launch_bounds__(256) void gate_kernel(
    float* __restrict__ y, const float* __restrict__ xz)
{
    int idx = blockIdx.x * 256 + threadIdx.x;
    if (idx >= BL * DINNER) return;
    int d = idx & (DINNER - 1);
    int m = idx >> 11;
    float z = xz[(size_t)m * XZ_N + DINNER + d];
    y[idx] *= z / (1.f + expf(-z));
}

// ---------------------------------------------------------------------------
extern "C" void kernel_launch(void* const* d_in, const int* in_sizes, int n_in,
                              void* d_out, int out_size, void* d_ws, size_t ws_size,
                              hipStream_t stream)
{
    const float* x     = (const float*)d_in[0];
    const float* in_w  = (const float*)d_in[1];   // [NL, 4096, 1024]
    const float* cw    = (const float*)d_in[2];   // [NL, 2048, 4]
    const float* cb    = (const float*)d_in[3];   // [NL, 2048]
    const float* xp_w  = (const float*)d_in[4];   // [NL, 192, 2048]
    const float* dt_w  = (const float*)d_in[5];   // [NL, 2048, 64]
    const float* dt_b  = (const float*)d_in[6];   // [NL, 2048]
    const float* A_log = (const float*)d_in[7];   // [NL, 2048, 64]
    const float* D_sk  = (const float*)d_in[8];   // [NL, 2048]
    const float* out_w = (const float*)d_in[9];   // [NL, 1024, 2048]
    float* out_final = (float*)d_out;

    float* ws = (float*)d_ws;
    float* xz   = ws;                               // [2048, 4096]  32 MB
    float* ub   = xz + (size_t)BL * XZ_N;           // [2048, 2048]  16 MB
    float* xd   = ub + (size_t)BL * DINNER;         // [2048, 192]  1.5 MB
    float* dtb  = xd + (size_t)BL * XDBL_N;         // [2048, 2048]  16 MB
    float* yb   = dtb + (size_t)BL * DINNER;        // [2048, 2048]  16 MB
    float* lay  = yb + (size_t)BL * DINNER;         // [2048, 1024]   8 MB

    for (int layer = 0; layer < NLAYERS; ++layer) {
        const float* xin = (layer == 0) ? x : lay;
        float* outp = (layer == NLAYERS - 1) ? out_final : lay;

        // 1. xz = xin @ in_w^T   [2048, 4096]
        gemm_nt<0><<<dim3(XZ_N / 64, BL / 64), 256, 0, stream>>>(
            xin, DMODEL, in_w + (size_t)layer * XZ_N * DMODEL, nullptr,
            xz, XZ_N, DMODEL);

        // 2. u = silu(dwconv(xz[:, :2048]))
        conv_silu_kernel<<<(BL * DINNER) / 256, 256, 0, stream>>>(
            xz, cw + (size_t)layer * DINNER * 4, cb + (size_t)layer * DINNER, ub);

        // 3. x_dbl = u @ xp_w^T   [2048, 192]
        gemm_nt<0><<<dim3(XDBL_N / 64, BL / 64), 256, 0, stream>>>(
            ub, DINNER, xp_w + (size_t)layer * XDBL_N * DINNER, nullptr,
            xd, XDBL_N, DINNER);

        // 4. dt = softplus(x_dbl[:, :64] @ dt_w^T + dt_b)   [2048, 2048]
        gemm_nt<1><<<dim3(DINNER / 64, BL / 64), 256, 0, stream>>>(
            xd, XDBL_N, dt_w + (size_t)layer * DINNER * DTRANK,
            dt_b + (size_t)layer * DINNER, dtb, DINNER, DTRANK);

        // 5. selective scan -> yb
        scan_kernel<<<(BATCH * DINNER) / 4, 256, 0, stream>>>(
            ub, dtb, xd, A_log + (size_t)layer * DINNER * DSTATE,
            D_sk + (size_t)layer * DINNER, yb);

        // 6. yb *= silu(z)
        gate_kernel<<<(BL * DINNER) / 256, 256, 0, stream>>>(yb, xz);

        // 7. out = yb @ out_w^T   [2048, 1024]
        gemm_nt<0><<<dim3(DMODEL / 64, BL / 64), 256, 0, stream>>>(
            yb, DINNER, out_w + (size_t)layer * DMODEL * DINNER, nullptr,
            outp, DMODEL, DINNER);
    }
}

// Round 2
// 1366.774 us; speedup vs baseline: 1.4622x; 1.4622x over previous
//
#include <hip/hip_runtime.h>
#include <hip/hip_bf16.h>
#include <math.h>

// ---- problem constants ----
#define BATCH   2
#define SEQLEN  1024
#define DMODEL  1024
#define DINNER  2048
#define DSTATE  64
#define DTRANK  64
#define NLAYERS 2
#define BL      (BATCH * SEQLEN)          // 2048 rows
#define XZ_N    (2 * DINNER)              // 4096
#define XDBL_N  (DTRANK + 2 * DSTATE)     // 192

typedef __hip_bfloat16 bf16;
typedef short bf16x8 __attribute__((ext_vector_type(8)));   // 8 bf16 (4 VGPRs)
typedef float f32x4  __attribute__((ext_vector_type(4)));

// async global->LDS, 16B per lane (dest = wave-uniform base + lane*16)
__device__ __forceinline__ void gload16(const void* g, void* l) {
    __builtin_amdgcn_global_load_lds(
        (__attribute__((address_space(1))) void*)(g),
        (__attribute__((address_space(3))) void*)(l), 16, 0, 0);
}

// ---------------------------------------------------------------------------
// bf16 MFMA GEMM: C[M,N] = A[M,K] * W[N,K]^T, f32 accum.
// 128x128 tile, BK=32, 256 thr (4 waves 2x2), 4x4 16x16x32 frags per wave.
// M,N multiples of 128; K multiple of 32.  (m97 structure)
// ---------------------------------------------------------------------------
template<bool WRITE_BF>
__global__ __launch_bounds__(256) void gemm_mfma(
    const bf16* __restrict__ A, int lda,
    const bf16* __restrict__ W, int ldw,
    float* __restrict__ C, bf16* __restrict__ Cb, int ldc, int K)
{
    __shared__ short As[128 * 32];
    __shared__ short Ws[128 * 32];
    const int tid = threadIdx.x;
    const int w = tid >> 6, l = tid & 63;
    const int m0 = blockIdx.y * 128, n0 = blockIdx.x * 128;
    const int wm = (w & 1) * 64, wn = (w >> 1) * 64;

    // staging: each wave-inst covers 16 rows x 32 bf16 (1KB); 2 insts each for A,W
    const int srow = w * 16 + (l >> 2);       // 0..63 (inst1 adds 64)
    const int scol = (l & 3) * 8;             // element offset within row
    const bf16* Ag = A + (size_t)(m0 + srow) * lda + scol;
    const bf16* Wg = W + (size_t)(n0 + srow) * ldw + scol;
    short* Asb = &As[w * 512];
    short* Wsb = &Ws[w * 512];

    const int fr = l & 15, fq = l >> 4;
    f32x4 acc[4][4] = {};

    for (int k0 = 0; k0 < K; k0 += 32) {
        gload16(Ag + k0,                      Asb);
        gload16(Ag + (size_t)64 * lda + k0,   Asb + 64 * 32);
        gload16(Wg + k0,                      Wsb);
        gload16(Wg + (size_t)64 * ldw + k0,   Wsb + 64 * 32);
        __syncthreads();   // drains vmcnt before barrier

        bf16x8 af[4], bfr[4];
#pragma unroll
        for (int m = 0; m < 4; ++m)
            af[m] = *(const bf16x8*)&As[(wm + m * 16 + fr) * 32 + fq * 8];
#pragma unroll
        for (int n = 0; n < 4; ++n)
            bfr[n] = *(const bf16x8*)&Ws[(wn + n * 16 + fr) * 32 + fq * 8];
#pragma unroll
        for (int m = 0; m < 4; ++m)
#pragma unroll
            for (int n = 0; n < 4; ++n)
                acc[m][n] = __builtin_amdgcn_mfma_f32_16x16x32_bf16(
                    af[m], bfr[n], acc[m][n], 0, 0, 0);
        __syncthreads();
    }

    // C/D layout: col = lane&15, row = (lane>>4)*4 + j
#pragma unroll
    for (int m = 0; m < 4; ++m) {
        const int grow = m0 + wm + m * 16 + fq * 4;
#pragma unroll
        for (int n = 0; n < 4; ++n) {
            const int gcol = n0 + wn + n * 16 + fr;
#pragma unroll
            for (int j = 0; j < 4; ++j) {
                float v = acc[m][n][j];
                C[(size_t)(grow + j) * ldc + gcol] = v;
                if (WRITE_BF)
                    Cb[(size_t)(grow + j) * ldc + gcol] = __float2bfloat16(v);
            }
        }
    }
}

// ---------------------------------------------------------------------------
// f32 tiled GEMM (kept for the small x_proj / dt_proj to limit bf16 error).
// ---------------------------------------------------------------------------
template<int EPI>
__global__ __launch_bounds__(256) void gemm_nt(
    const float* __restrict__ A, int lda,
    const float* __restrict__ W,
    const float* __restrict__ bias,
    float* __restrict__ C, int ldc, int K)
{
    __shared__ float As[16][68];
    __shared__ float Ws[16][68];
    const int tid = threadIdx.x;
    const int tx = tid & 15, ty = tid >> 4;
    const int m0 = blockIdx.y * 64, n0 = blockIdx.x * 64;
    const int lr = tid >> 2;
    const int lk = (tid & 3) << 2;

    const float* Ap = A + (size_t)(m0 + lr) * lda + lk;
    const float* Wp = W + (size_t)(n0 + lr) * K + lk;

    float acc[4][4] = {};

    for (int k0 = 0; k0 < K; k0 += 16) {
        float4 av = *(const float4*)(Ap + k0);
        float4 wv = *(const float4*)(Wp + k0);
        As[lk + 0][lr] = av.x; As[lk + 1][lr] = av.y;
        As[lk + 2][lr] = av.z; As[lk + 3][lr] = av.w;
        Ws[lk + 0][lr] = wv.x; Ws[lk + 1][lr] = wv.y;
        Ws[lk + 2][lr] = wv.z; Ws[lk + 3][lr] = wv.w;
        __syncthreads();
#pragma unroll
        for (int kk = 0; kk < 16; ++kk) {
            float4 a = *(const float4*)&As[kk][ty << 2];
            float4 b = *(const float4*)&Ws[kk][tx << 2];
            acc[0][0] += a.x * b.x; acc[0][1] += a.x * b.y;
            acc[0][2] += a.x * b.z; acc[0][3] += a.x * b.w;
            acc[1][0] += a.y * b.x; acc[1][1] += a.y * b.y;
            acc[1][2] += a.y * b.z; acc[1][3] += a.y * b.w;
            acc[2][0] += a.z * b.x; acc[2][1] += a.z * b.y;
            acc[2][2] += a.z * b.z; acc[2][3] += a.z * b.w;
            acc[3][0] += a.w * b.x; acc[3][1] += a.w * b.y;
            acc[3][2] += a.w * b.z; acc[3][3] += a.w * b.w;
        }
        __syncthreads();
    }

    const int n = n0 + (tx << 2);
#pragma unroll
    for (int i = 0; i < 4; ++i) {
        float4 v = make_float4(acc[i][0], acc[i][1], acc[i][2], acc[i][3]);
        if (EPI == 1) {
            v.x += bias[n + 0]; v.y += bias[n + 1];
            v.z += bias[n + 2]; v.w += bias[n + 3];
            v.x = v.x > 20.f ? v.x : log1pf(expf(v.x));
            v.y = v.y > 20.f ? v.y : log1pf(expf(v.y));
            v.z = v.z > 20.f ? v.z : log1pf(expf(v.z));
            v.w = v.w > 20.f ? v.w : log1pf(expf(v.w));
        }
        *(float4*)&C[(size_t)(m0 + (ty << 2) + i) * ldc + n] = v;
    }
}

// ---------------------------------------------------------------------------
// f32 -> bf16 convert (vector of 4)
// ---------------------------------------------------------------------------
__global__ __launch_bounds__(256) void cvt_bf16_kernel(
    const float* __restrict__ in, bf16* __restrict__ out, int n4)
{
    int i = blockIdx.x * 256 + threadIdx.x;
    if (i >= n4) return;
    float4 v = ((const float4*)in)[i];
    union { bf16 b[4]; uint2 u; } r;
    r.b[0] = __float2bfloat16(v.x); r.b[1] = __float2bfloat16(v.y);
    r.b[2] = __float2bfloat16(v.z); r.b[3] = __float2bfloat16(v.w);
    ((uint2*)out)[i] = r.u;
}

// ---------------------------------------------------------------------------
// Causal depthwise conv (K=4) + bias + SiLU (reads u-half of xz)
// ---------------------------------------------------------------------------
__global__ __launch_bounds__(256) void conv_silu_kernel(
    const float* __restrict__ xz, const float* __restrict__ cw,
    const float* __restrict__ cb, float* __restrict__ u)
{
    int idx = blockIdx.x * 256 + threadIdx.x;
    if (idx >= BL * DINNER) return;
    int d = idx & (DINNER - 1);
    int m = idx >> 11;
    int t = m & (SEQLEN - 1);
    float acc = cb[d];
#pragma unroll
    for (int k = 0; k < 4; ++k) {
        int tt = t - 3 + k;
        if (tt >= 0)
            acc += xz[(size_t)(m - 3 + k) * XZ_N + d] * cw[d * 4 + k];
    }
    u[idx] = acc / (1.f + expf(-acc));
}

// ---------------------------------------------------------------------------
// Selective scan: one wave per (b,d) channel, lane = state (dS=64)
// ---------------------------------------------------------------------------
__global__ __launch_bounds__(256) void scan_kernel(
    const float* __restrict__ u,
    const float* __restrict__ dt,
    const float* __restrict__ xdbl,
    const float* __restrict__ A_log,
    const float* __restrict__ D_skip,
    float* __restrict__ y)
{
    const int wave = threadIdx.x >> 6;
    const int lane = threadIdx.x & 63;
    const int c = blockIdx.x * 4 + wave;
    const int b = c >> 11;
    const int d = c & (DINNER - 1);

    const float Av = -expf(A_log[d * DSTATE + lane]);
    const float Dk = D_skip[d];

    const float* dt_p = dt + (size_t)b * SEQLEN * DINNER + d;
    const float* u_p  = u  + (size_t)b * SEQLEN * DINNER + d;
    const float* bc_p = xdbl + (size_t)b * SEQLEN * XDBL_N + DTRANK + lane;
    float* y_p = y + (size_t)b * SEQLEN * DINNER + d;

    float h = 0.f;
    float dtv = dt_p[0];
    float uv  = u_p[0];
    float Bt  = bc_p[0];
    float Ct  = bc_p[DSTATE];

    for (int t = 0; t < SEQLEN; ++t) {
        float dtn = 0.f, un = 0.f, Bn = 0.f, Cn = 0.f;
        if (t < SEQLEN - 1) {
            dtn = dt_p[(t + 1) * DINNER];
            un  = u_p[(t + 1) * DINNER];
            Bn  = bc_p[(t + 1) * XDBL_N];
            Cn  = bc_p[(t + 1) * XDBL_N + DSTATE];
        }
        float dA = __expf(dtv * Av);
        h = h * dA + (dtv * uv) * Bt;
        float p = h * Ct;
#pragma unroll
        for (int off = 32; off; off >>= 1) p += __shfl_xor(p, off, 64);
        if (lane == 0) y_p[t * DINNER] = p + uv * Dk;
        dtv = dtn; uv = un; Bt = Bn; Ct = Cn;
    }
}

// ---------------------------------------------------------------------------
// Gate: y_bf16 = y * silu(z)   (bf16 output feeds out_proj MFMA)
// ---------------------------------------------------------------------------
__global__ __launch_bounds__(256) void gate_kernel(
    const float* __restrict__ y, const float* __restrict__ xz,
    bf16* __restrict__ yb16)
{
    int idx = blockIdx.x * 256 + threadIdx.x;
    if (idx >= BL * DINNER) return;
    int d = idx & (DINNER - 1);
    int m = idx >> 11;
    float z = xz[(size_t)m * XZ_N + DINNER + d];
    yb16[idx] = __float2bfloat16(y[idx] * z / (1.f + expf(-z)));
}

// ---------------------------------------------------------------------------
extern "C" void kernel_launch(void* const* d_in, const int* in_sizes, int n_in,
                              void* d_out, int out_size, void* d_ws, size_t ws_size,
                              hipStream_t stream)
{
    const float* x     = (const float*)d_in[0];
    const float* in_w  = (const float*)d_in[1];   // [NL, 4096, 1024]
    const float* cw    = (const float*)d_in[2];   // [NL, 2048, 4]
    const float* cb    = (const float*)d_in[3];   // [NL, 2048]
    const float* xp_w  = (const float*)d_in[4];   // [NL, 192, 2048]
    const float* dt_w  = (const float*)d_in[5];   // [NL, 2048, 64]
    const float* dt_b  = (const float*)d_in[6];   // [NL, 2048]
    const float* A_log = (const float*)d_in[7];   // [NL, 2048, 64]
    const float* D_sk  = (const float*)d_in[8];   // [NL, 2048]
    const float* out_w = (const float*)d_in[9];   // [NL, 1024, 2048]
    float* out_final = (float*)d_out;

    float* ws = (float*)d_ws;
    float* xz   = ws;                               // [2048,4096]
    float* ub   = xz  + (size_t)BL * XZ_N;          // [2048,2048]
    float* xd   = ub  + (size_t)BL * DINNER;        // [2048,192]
    float* dtb  = xd  + (size_t)BL * XDBL_N;        // [2048,2048]
    float* yb   = dtb + (size_t)BL * DINNER;        // [2048,2048]
    float* lay  = yb  + (size_t)BL * DINNER;        // [2048,1024]

    bf16* bp = (bf16*)(lay + (size_t)BL * DMODEL);
    bf16* inw_bf  = bp;  bp += (size_t)NLAYERS * XZ_N * DMODEL;    // 8.4M
    bf16* outw_bf = bp;  bp += (size_t)NLAYERS * DMODEL * DINNER;  // 4.2M
    bf16* xin_bf  = bp;  bp += (size_t)BL * DMODEL;                // 2.1M
    bf16* y_bf    = bp;  bp += (size_t)BL * DINNER;                // 4.2M

    // weight + input conversions (every call; deterministic)
    {
        int n4 = NLAYERS * XZ_N * DMODEL / 4;
        cvt_bf16_kernel<<<(n4 + 255) / 256, 256, 0, stream>>>(in_w, inw_bf, n4);
        n4 = NLAYERS * DMODEL * DINNER / 4;
        cvt_bf16_kernel<<<(n4 + 255) / 256, 256, 0, stream>>>(out_w, outw_bf, n4);
        n4 = BL * DMODEL / 4;
        cvt_bf16_kernel<<<(n4 + 255) / 256, 256, 0, stream>>>(x, xin_bf, n4);
    }

    for (int layer = 0; layer < NLAYERS; ++layer) {
        float* outp = (layer == NLAYERS - 1) ? out_final : lay;

        // 1. xz = xin @ in_w^T  (bf16 MFMA)  [2048,4096]
        gemm_mfma<false><<<dim3(XZ_N / 128, BL / 128), 256, 0, stream>>>(
            xin_bf, DMODEL, inw_bf + (size_t)layer * XZ_N * DMODEL,
            DMODEL, xz, nullptr, XZ_N, DMODEL);

        // 2. u = silu(dwconv(xz[:, :2048]))
        conv_silu_kernel<<<(BL * DINNER) / 256, 256, 0, stream>>>(
            xz, cw + (size_t)layer * DINNER * 4, cb + (size_t)layer * DINNER, ub);

        // 3. x_dbl = u @ xp_w^T  (f32)  [2048,192]
        gemm_nt<0><<<dim3(XDBL_N / 64, BL / 64), 256, 0, stream>>>(
            ub, DINNER, xp_w + (size_t)layer * XDBL_N * DINNER, nullptr,
            xd, XDBL_N, DINNER);

        // 4. dt = softplus(x_dbl[:, :64] @ dt_w^T + dt_b)  (f32)  [2048,2048]
        gemm_nt<1><<<dim3(DINNER / 64, BL / 64), 256, 0, stream>>>(
            xd, XDBL_N, dt_w + (size_t)layer * DINNER * DTRANK,
            dt_b + (size_t)layer * DINNER, dtb, DINNER, DTRANK);

        // 5. selective scan -> yb (f32)
        scan_kernel<<<(BATCH * DINNER) / 4, 256, 0, stream>>>(
            ub, dtb, xd, A_log + (size_t)layer * DINNER * DSTATE,
            D_sk + (size_t)layer * DINNER, yb);

        // 6. y_bf = yb * silu(z)
        gate_kernel<<<(BL * DINNER) / 256, 256, 0, stream>>>(yb, xz, y_bf);

        // 7. out = y @ out_w^T  (bf16 MFMA)  [2048,1024]
        if (layer == NLAYERS - 1)
            gemm_mfma<false><<<dim3(DMODEL / 128, BL / 128), 256, 0, stream>>>(
                y_bf, DINNER, outw_bf + (size_t)layer * DMODEL * DINNER,
                DINNER, outp, nullptr, DMODEL, DINNER);
        else
            gemm_mfma<true><<<dim3(DMODEL / 128, BL / 128), 256, 0, stream>>>(
                y_bf, DINNER, outw_bf + (size_t)layer * DMODEL * DINNER,
                DINNER, outp, xin_bf, DMODEL, DINNER);
    }
}

// Round 3
// 1181.001 us; speedup vs baseline: 1.6922x; 1.1573x over previous
//
#include <hip/hip_runtime.h>
#include <hip/hip_bf16.h>
#include <math.h>

// ---- problem constants ----
#define BATCH   2
#define SEQLEN  1024
#define DMODEL  1024
#define DINNER  2048
#define DSTATE  64
#define DTRANK  64
#define NLAYERS 2
#define BL      (BATCH * SEQLEN)          // 2048 rows
#define XZ_N    (2 * DINNER)              // 4096
#define XDBL_N  (DTRANK + 2 * DSTATE)     // 192
#define NCH     16                        // scan chunks per sequence
#define CLEN    (SEQLEN / NCH)            // 64 steps per chunk

typedef __hip_bfloat16 bf16;
typedef short bf16x8 __attribute__((ext_vector_type(8)));
typedef float f32x4  __attribute__((ext_vector_type(4)));

// async global->LDS, 16B per lane
__device__ __forceinline__ void gload16(const void* g, void* l) {
    __builtin_amdgcn_global_load_lds(
        (__attribute__((address_space(1))) void*)(g),
        (__attribute__((address_space(3))) void*)(l), 16, 0, 0);
}

// 64-lane sum via DPP (pure VALU, no LDS unit). Result valid in lane 63.
__device__ __forceinline__ float dpp_sum64(float x) {
    float r = x;
    int v;
    v = __builtin_amdgcn_update_dpp(0, __float_as_int(r), 0x111, 0xf, 0xf, true); r += __int_as_float(v); // row_shr:1
    v = __builtin_amdgcn_update_dpp(0, __float_as_int(r), 0x112, 0xf, 0xf, true); r += __int_as_float(v); // row_shr:2
    v = __builtin_amdgcn_update_dpp(0, __float_as_int(r), 0x114, 0xf, 0xf, true); r += __int_as_float(v); // row_shr:4
    v = __builtin_amdgcn_update_dpp(0, __float_as_int(r), 0x118, 0xf, 0xf, true); r += __int_as_float(v); // row_shr:8
    v = __builtin_amdgcn_update_dpp(0, __float_as_int(r), 0x142, 0xa, 0xf, true); r += __int_as_float(v); // row_bcast:15
    v = __builtin_amdgcn_update_dpp(0, __float_as_int(r), 0x143, 0xc, 0xf, true); r += __int_as_float(v); // row_bcast:31
    return r;
}

// ---------------------------------------------------------------------------
// bf16 MFMA GEMM: C[M,N] = A[M,K] * W[N,K]^T, f32 accum. 128x128 tile, BK=32.
// ---------------------------------------------------------------------------
template<bool WRITE_BF>
__global__ __launch_bounds__(256) void gemm_mfma(
    const bf16* __restrict__ A, int lda,
    const bf16* __restrict__ W, int ldw,
    float* __restrict__ C, bf16* __restrict__ Cb, int ldc, int K)
{
    __shared__ short As[128 * 32];
    __shared__ short Ws[128 * 32];
    const int tid = threadIdx.x;
    const int w = tid >> 6, l = tid & 63;
    const int m0 = blockIdx.y * 128, n0 = blockIdx.x * 128;
    const int wm = (w & 1) * 64, wn = (w >> 1) * 64;

    const int srow = w * 16 + (l >> 2);
    const int scol = (l & 3) * 8;
    const bf16* Ag = A + (size_t)(m0 + srow) * lda + scol;
    const bf16* Wg = W + (size_t)(n0 + srow) * ldw + scol;
    short* Asb = &As[w * 512];
    short* Wsb = &Ws[w * 512];

    const int fr = l & 15, fq = l >> 4;
    f32x4 acc[4][4] = {};

    for (int k0 = 0; k0 < K; k0 += 32) {
        gload16(Ag + k0,                      Asb);
        gload16(Ag + (size_t)64 * lda + k0,   Asb + 64 * 32);
        gload16(Wg + k0,                      Wsb);
        gload16(Wg + (size_t)64 * ldw + k0,   Wsb + 64 * 32);
        __syncthreads();

        bf16x8 af[4], bfr[4];
#pragma unroll
        for (int m = 0; m < 4; ++m)
            af[m] = *(const bf16x8*)&As[(wm + m * 16 + fr) * 32 + fq * 8];
#pragma unroll
        for (int n = 0; n < 4; ++n)
            bfr[n] = *(const bf16x8*)&Ws[(wn + n * 16 + fr) * 32 + fq * 8];
#pragma unroll
        for (int m = 0; m < 4; ++m)
#pragma unroll
            for (int n = 0; n < 4; ++n)
                acc[m][n] = __builtin_amdgcn_mfma_f32_16x16x32_bf16(
                    af[m], bfr[n], acc[m][n], 0, 0, 0);
        __syncthreads();
    }

#pragma unroll
    for (int m = 0; m < 4; ++m) {
        const int grow = m0 + wm + m * 16 + fq * 4;
#pragma unroll
        for (int n = 0; n < 4; ++n) {
            const int gcol = n0 + wn + n * 16 + fr;
#pragma unroll
            for (int j = 0; j < 4; ++j) {
                float v = acc[m][n][j];
                C[(size_t)(grow + j) * ldc + gcol] = v;
                if (WRITE_BF)
                    Cb[(size_t)(grow + j) * ldc + gcol] = __float2bfloat16(v);
            }
        }
    }
}

// ---------------------------------------------------------------------------
// f32 tiled GEMM (x_proj / dt_proj keep f32 for accuracy headroom)
// ---------------------------------------------------------------------------
template<int EPI>
__global__ __launch_bounds__(256) void gemm_nt(
    const float* __restrict__ A, int lda,
    const float* __restrict__ W,
    const float* __restrict__ bias,
    float* __restrict__ C, int ldc, int K)
{
    __shared__ float As[16][68];
    __shared__ float Ws[16][68];
    const int tid = threadIdx.x;
    const int tx = tid & 15, ty = tid >> 4;
    const int m0 = blockIdx.y * 64, n0 = blockIdx.x * 64;
    const int lr = tid >> 2;
    const int lk = (tid & 3) << 2;

    const float* Ap = A + (size_t)(m0 + lr) * lda + lk;
    const float* Wp = W + (size_t)(n0 + lr) * K + lk;

    float acc[4][4] = {};

    for (int k0 = 0; k0 < K; k0 += 16) {
        float4 av = *(const float4*)(Ap + k0);
        float4 wv = *(const float4*)(Wp + k0);
        As[lk + 0][lr] = av.x; As[lk + 1][lr] = av.y;
        As[lk + 2][lr] = av.z; As[lk + 3][lr] = av.w;
        Ws[lk + 0][lr] = wv.x; Ws[lk + 1][lr] = wv.y;
        Ws[lk + 2][lr] = wv.z; Ws[lk + 3][lr] = wv.w;
        __syncthreads();
#pragma unroll
        for (int kk = 0; kk < 16; ++kk) {
            float4 a = *(const float4*)&As[kk][ty << 2];
            float4 b = *(const float4*)&Ws[kk][tx << 2];
            acc[0][0] += a.x * b.x; acc[0][1] += a.x * b.y;
            acc[0][2] += a.x * b.z; acc[0][3] += a.x * b.w;
            acc[1][0] += a.y * b.x; acc[1][1] += a.y * b.y;
            acc[1][2] += a.y * b.z; acc[1][3] += a.y * b.w;
            acc[2][0] += a.z * b.x; acc[2][1] += a.z * b.y;
            acc[2][2] += a.z * b.z; acc[2][3] += a.z * b.w;
            acc[3][0] += a.w * b.x; acc[3][1] += a.w * b.y;
            acc[3][2] += a.w * b.z; acc[3][3] += a.w * b.w;
        }
        __syncthreads();
    }

    const int n = n0 + (tx << 2);
#pragma unroll
    for (int i = 0; i < 4; ++i) {
        float4 v = make_float4(acc[i][0], acc[i][1], acc[i][2], acc[i][3]);
        if (EPI == 1) {
            v.x += bias[n + 0]; v.y += bias[n + 1];
            v.z += bias[n + 2]; v.w += bias[n + 3];
            v.x = v.x > 20.f ? v.x : log1pf(expf(v.x));
            v.y = v.y > 20.f ? v.y : log1pf(expf(v.y));
            v.z = v.z > 20.f ? v.z : log1pf(expf(v.z));
            v.w = v.w > 20.f ? v.w : log1pf(expf(v.w));
        }
        *(float4*)&C[(size_t)(m0 + (ty << 2) + i) * ldc + n] = v;
    }
}

// ---------------------------------------------------------------------------
__global__ __launch_bounds__(256) void cvt_bf16_kernel(
    const float* __restrict__ in, bf16* __restrict__ out, int n4)
{
    int i = blockIdx.x * 256 + threadIdx.x;
    if (i >= n4) return;
    float4 v = ((const float4*)in)[i];
    union { bf16 b[4]; uint2 u; } r;
    r.b[0] = __float2bfloat16(v.x); r.b[1] = __float2bfloat16(v.y);
    r.b[2] = __float2bfloat16(v.z); r.b[3] = __float2bfloat16(v.w);
    ((uint2*)out)[i] = r.u;
}

// ---------------------------------------------------------------------------
__global__ __launch_bounds__(256) void conv_silu_kernel(
    const float* __restrict__ xz, const float* __restrict__ cw,
    const float* __restrict__ cb, float* __restrict__ u)
{
    int idx = blockIdx.x * 256 + threadIdx.x;
    if (idx >= BL * DINNER) return;
    int d = idx & (DINNER - 1);
    int m = idx >> 11;
    int t = m & (SEQLEN - 1);
    float acc = cb[d];
#pragma unroll
    for (int k = 0; k < 4; ++k) {
        int tt = t - 3 + k;
        if (tt >= 0)
            acc += xz[(size_t)(m - 3 + k) * XZ_N + d] * cw[d * 4 + k];
    }
    u[idx] = acc / (1.f + expf(-acc));
}

// ---------------------------------------------------------------------------
// Chunked selective scan.
// Pass 1: per (b,d,chunk) wave (lane = state): local scan with h0=0 ->
//         q = h at chunk end, P = prod of dA over chunk (log-space).
// Pass 2: per (b,d,s) thread: sequential combine over 16 chunks; q becomes
//         the chunk's true start state (Hstart).
// Pass 3: replay chunk from Hstart, DPP-reduce y, lane 63 writes.
// ---------------------------------------------------------------------------
__global__ __launch_bounds__(256) void scan_pass1(
    const float* __restrict__ u, const float* __restrict__ dt,
    const float* __restrict__ xdbl, const float* __restrict__ A_log,
    float* __restrict__ q, float* __restrict__ P)
{
    const int wave = threadIdx.x >> 6, lane = threadIdx.x & 63;
    const int w = blockIdx.x * 4 + wave;
    const int c = w & (NCH - 1);
    const int bd = w >> 4;
    const int b = bd >> 11, d = bd & (DINNER - 1);
    const float Av = -expf(A_log[d * DSTATE + lane]);
    const int row0 = b * SEQLEN + c * CLEN;
    const float* dt_p = dt + (size_t)row0 * DINNER + d;
    const float* u_p  = u  + (size_t)row0 * DINNER + d;
    const float* bc_p = xdbl + (size_t)row0 * XDBL_N + DTRANK + lane;

    float h = 0.f, lp = 0.f;
    float dtv = dt_p[0], uv = u_p[0], Bt = bc_p[0];
    for (int t = 0; t < CLEN; ++t) {
        const int tn = (t + 1 < CLEN) ? t + 1 : t;
        float dtn = dt_p[tn * DINNER];
        float un  = u_p[tn * DINNER];
        float Bn  = bc_p[tn * XDBL_N];
        float e = dtv * Av;
        lp += e;
        h = h * __expf(e) + (dtv * uv) * Bt;
        dtv = dtn; uv = un; Bt = Bn;
    }
    const size_t o = ((size_t)bd * NCH + c) * DSTATE + lane;
    q[o] = h;
    P[o] = __expf(lp);
}

__global__ __launch_bounds__(256) void scan_pass2(
    float* __restrict__ q, const float* __restrict__ P)
{
    const int idx = blockIdx.x * 256 + threadIdx.x;   // B*DINNER*DSTATE
    const int bd = idx >> 6, s = idx & 63;
    float H = 0.f;
    size_t o = (size_t)bd * NCH * DSTATE + s;
    for (int c = 0; c < NCH; ++c, o += DSTATE) {
        float qq = q[o], pp = P[o];
        q[o] = H;                    // becomes Hstart for chunk c
        H = qq + pp * H;
    }
}

__global__ __launch_bounds__(256) void scan_pass3(
    const float* __restrict__ u, const float* __restrict__ dt,
    const float* __restrict__ xdbl, const float* __restrict__ A_log,
    const float* __restrict__ D_skip, const float* __restrict__ Hs,
    float* __restrict__ y)
{
    const int wave = threadIdx.x >> 6, lane = threadIdx.x & 63;
    const int w = blockIdx.x * 4 + wave;
    const int c = w & (NCH - 1);
    const int bd = w >> 4;
    const int b = bd >> 11, d = bd & (DINNER - 1);
    const float Av = -expf(A_log[d * DSTATE + lane]);
    const float Dk = D_skip[d];
    const int row0 = b * SEQLEN + c * CLEN;
    const float* dt_p = dt + (size_t)row0 * DINNER + d;
    const float* u_p  = u  + (size_t)row0 * DINNER + d;
    const float* bc_p = xdbl + (size_t)row0 * XDBL_N + DTRANK + lane;
    float* y_p = y + (size_t)row0 * DINNER + d;

    float h = Hs[((size_t)bd * NCH + c) * DSTATE + lane];
    float dtv = dt_p[0], uv = u_p[0], Bt = bc_p[0], Ct = bc_p[DSTATE];
    for (int t = 0; t < CLEN; ++t) {
        const int tn = (t + 1 < CLEN) ? t + 1 : t;
        float dtn = dt_p[tn * DINNER];
        float un  = u_p[tn * DINNER];
        float Bn  = bc_p[tn * XDBL_N];
        float Cn  = bc_p[tn * XDBL_N + DSTATE];
        float dA = __expf(dtv * Av);
        h = h * dA + (dtv * uv) * Bt;
        float r = dpp_sum64(h * Ct);
        if (lane == 63) y_p[t * DINNER] = r + uv * Dk;
        dtv = dtn; uv = un; Bt = Bn; Ct = Cn;
    }
}

// ---------------------------------------------------------------------------
__global__ __launch_bounds__(256) void gate_kernel(
    const float* __restrict__ y, const float* __restrict__ xz,
    bf16* __restrict__ yb16)
{
    int idx = blockIdx.x * 256 + threadIdx.x;
    if (idx >= BL * DINNER) return;
    int d = idx & (DINNER - 1);
    int m = idx >> 11;
    float z = xz[(size_t)m * XZ_N + DINNER + d];
    yb16[idx] = __float2bfloat16(y[idx] * z / (1.f + expf(-z)));
}

// ---------------------------------------------------------------------------
extern "C" void kernel_launch(void* const* d_in, const int* in_sizes, int n_in,
                              void* d_out, int out_size, void* d_ws, size_t ws_size,
                              hipStream_t stream)
{
    const float* x     = (const float*)d_in[0];
    const float* in_w  = (const float*)d_in[1];
    const float* cw    = (const float*)d_in[2];
    const float* cb    = (const float*)d_in[3];
    const float* xp_w  = (const float*)d_in[4];
    const float* dt_w  = (const float*)d_in[5];
    const float* dt_b  = (const float*)d_in[6];
    const float* A_log = (const float*)d_in[7];
    const float* D_sk  = (const float*)d_in[8];
    const float* out_w = (const float*)d_in[9];
    float* out_final = (float*)d_out;

    float* ws = (float*)d_ws;
    float* xz   = ws;                               // [2048,4096]
    float* ub   = xz  + (size_t)BL * XZ_N;          // [2048,2048]
    float* xd   = ub  + (size_t)BL * DINNER;        // [2048,192]
    float* dtb  = xd  + (size_t)BL * XDBL_N;        // [2048,2048]
    float* yb   = dtb + (size_t)BL * DINNER;        // [2048,2048]
    float* lay  = yb  + (size_t)BL * DINNER;        // [2048,1024]

    bf16* bp = (bf16*)(lay + (size_t)BL * DMODEL);
    bf16* inw_bf  = bp;  bp += (size_t)NLAYERS * XZ_N * DMODEL;
    bf16* outw_bf = bp;  bp += (size_t)NLAYERS * DMODEL * DINNER;
    bf16* xin_bf  = bp;  bp += (size_t)BL * DMODEL;
    bf16* y_bf    = bp;  bp += (size_t)BL * DINNER;

    float* qbuf = (float*)bp;                              // [4096,16,64]
    float* Pbuf = qbuf + (size_t)BATCH * DINNER * NCH * DSTATE;

    {
        int n4 = NLAYERS * XZ_N * DMODEL / 4;
        cvt_bf16_kernel<<<(n4 + 255) / 256, 256, 0, stream>>>(in_w, inw_bf, n4);
        n4 = NLAYERS * DMODEL * DINNER / 4;
        cvt_bf16_kernel<<<(n4 + 255) / 256, 256, 0, stream>>>(out_w, outw_bf, n4);
        n4 = BL * DMODEL / 4;
        cvt_bf16_kernel<<<(n4 + 255) / 256, 256, 0, stream>>>(x, xin_bf, n4);
    }

    for (int layer = 0; layer < NLAYERS; ++layer) {
        float* outp = (layer == NLAYERS - 1) ? out_final : lay;

        // 1. xz = xin @ in_w^T  (bf16 MFMA)
        gemm_mfma<false><<<dim3(XZ_N / 128, BL / 128), 256, 0, stream>>>(
            xin_bf, DMODEL, inw_bf + (size_t)layer * XZ_N * DMODEL,
            DMODEL, xz, nullptr, XZ_N, DMODEL);

        // 2. u = silu(dwconv(xz[:, :2048]))
        conv_silu_kernel<<<(BL * DINNER) / 256, 256, 0, stream>>>(
            xz, cw + (size_t)layer * DINNER * 4, cb + (size_t)layer * DINNER, ub);

        // 3. x_dbl = u @ xp_w^T  (f32)
        gemm_nt<0><<<dim3(XDBL_N / 64, BL / 64), 256, 0, stream>>>(
            ub, DINNER, xp_w + (size_t)layer * XDBL_N * DINNER, nullptr,
            xd, XDBL_N, DINNER);

        // 4. dt = softplus(x_dbl[:, :64] @ dt_w^T + dt_b)  (f32)
        gemm_nt<1><<<dim3(DINNER / 64, BL / 64), 256, 0, stream>>>(
            xd, XDBL_N, dt_w + (size_t)layer * DINNER * DTRANK,
            dt_b + (size_t)layer * DINNER, dtb, DINNER, DTRANK);

        // 5. chunked selective scan -> yb
        scan_pass1<<<BATCH * DINNER * NCH / 4, 256, 0, stream>>>(
            ub, dtb, xd, A_log + (size_t)layer * DINNER * DSTATE, qbuf, Pbuf);
        scan_pass2<<<BATCH * DINNER * DSTATE / 256, 256, 0, stream>>>(qbuf, Pbuf);
        scan_pass3<<<BATCH * DINNER * NCH / 4, 256, 0, stream>>>(
            ub, dtb, xd, A_log + (size_t)layer * DINNER * DSTATE,
            D_sk + (size_t)layer * DINNER, qbuf, yb);

        // 6. y_bf = yb * silu(z)
        gate_kernel<<<(BL * DINNER) / 256, 256, 0, stream>>>(yb, xz, y_bf);

        // 7. out = y @ out_w^T  (bf16 MFMA)
        if (layer == NLAYERS - 1)
            gemm_mfma<false><<<dim3(DMODEL / 128, BL / 128), 256, 0, stream>>>(
                y_bf, DINNER, outw_bf + (size_t)layer * DMODEL * DINNER,
                DINNER, outp, nullptr, DMODEL, DINNER);
        else
            gemm_mfma<true><<<dim3(DMODEL / 128, BL / 128), 256, 0, stream>>>(
                y_bf, DINNER, outw_bf + (size_t)layer * DMODEL * DINNER,
                DINNER, outp, xin_bf, DMODEL, DINNER);
    }
}